// Round 1
// baseline (241.421 us; speedup 1.0000x reference)
//
#include <hip/hip_runtime.h>
#include <hip/hip_bf16.h>
#include <stdint.h>

#define IN_F   2048
#define OUT_F  2048
#define NTOK   8192
#define KAUG   2176   // 2048 + E*R
#define RANKE  128    // E*R
#define SCALING 2.0f

typedef float  f32x4 __attribute__((ext_vector_type(4)));
typedef __bf16 bf16x8 __attribute__((ext_vector_type(8)));

__device__ __forceinline__ unsigned short f2b(float f) {
  union { float f; unsigned u; } v; v.f = f;
  return (unsigned short)((v.u + 0x7FFFu + ((v.u >> 16) & 1u)) >> 16);
}

__device__ __forceinline__ uint4 pack8(float4 a, float4 b) {
  uint4 p;
  p.x = f2b(a.x) | ((unsigned)f2b(a.y) << 16);
  p.y = f2b(a.z) | ((unsigned)f2b(a.w) << 16);
  p.z = f2b(b.x) | ((unsigned)f2b(b.y) << 16);
  p.w = f2b(b.z) | ((unsigned)f2b(b.w) << 16);
  return p;
}

// x [8192][2048] f32 -> bf16 into A' rows (stride KAUG), cols 0:2048
__global__ void k_convert_x(const float* __restrict__ x, unsigned short* __restrict__ Ap) {
  int n = blockIdx.x;
  int c = threadIdx.x * 8;
  const float4* src = (const float4*)(x + (size_t)n * IN_F + c);
  float4 a = src[0], b = src[1];
  *(uint4*)(Ap + (size_t)n * KAUG + c) = pack8(a, b);
}

// B'[o][0:2048]=weight[o][:], B'[o][2048+e*16+r]=lora_B[e][o][r]
__global__ void k_build_B(const float* __restrict__ w, const float* __restrict__ lb,
                          unsigned short* __restrict__ Bp) {
  int o = blockIdx.x;
  int t = threadIdx.x;
  int c = t * 8;
  const float4* src = (const float4*)(w + (size_t)o * IN_F + c);
  float4 a = src[0], b = src[1];
  *(uint4*)(Bp + (size_t)o * KAUG + c) = pack8(a, b);
  if (t < RANKE) {
    float v = lb[((size_t)(t >> 4) * OUT_F + o) * 16 + (t & 15)];
    Bp[(size_t)o * KAUG + IN_F + t] = f2b(v);
  }
}

// lora_A flat [8][16][2048] == [128][2048] -> bf16 Acat
__global__ void k_convert_A(const float* __restrict__ la, unsigned short* __restrict__ Ac) {
  int i = blockIdx.x;
  int c = threadIdx.x * 8;
  const float4* src = (const float4*)(la + (size_t)i * IN_F + c);
  float4 a = src[0], b = src[1];
  *(uint4*)(Ac + (size_t)i * IN_F + c) = pack8(a, b);
}

// Router: fp32 logits -> softmax -> top2 -> renorm; write SCALING*w dense [N][8]
// One wave handles 8 tokens; lane = e (0..7) + 8*p (partial group p=0..7).
__global__ void k_router(const float* __restrict__ x, const float* __restrict__ rw,
                         float* __restrict__ wsc) {
  int wave = threadIdx.x >> 6;
  int lane = threadIdx.x & 63;
  int e = lane & 7, p = lane >> 3;
  int t0 = (blockIdx.x * 4 + wave) * 8;
  for (int ti = 0; ti < 8; ++ti) {
    int n = t0 + ti;
    const float4* xr = (const float4*)(x + (size_t)n * IN_F) + p * 64;
    const float4* wr = (const float4*)(rw + (size_t)e * IN_F) + p * 64;
    float s = 0.f;
    #pragma unroll 8
    for (int i = 0; i < 64; ++i) {
      float4 a = xr[i], b = wr[i];
      s += a.x * b.x + a.y * b.y + a.z * b.z + a.w * b.w;
    }
    // reduce over partial groups (lane bits 3,4,5)
    s += __shfl_xor(s, 8);
    s += __shfl_xor(s, 16);
    s += __shfl_xor(s, 32);
    // softmax across e (lane bits 0,1,2)
    float m = s;
    m = fmaxf(m, __shfl_xor(m, 1));
    m = fmaxf(m, __shfl_xor(m, 2));
    m = fmaxf(m, __shfl_xor(m, 4));
    float ex = expf(s - m);
    float denom = ex;
    denom += __shfl_xor(denom, 1);
    denom += __shfl_xor(denom, 2);
    denom += __shfl_xor(denom, 4);
    float prob = ex / denom;
    // top-1 (lower index wins ties)
    float v1 = prob; int i1 = e;
    #pragma unroll
    for (int msk = 1; msk <= 4; msk <<= 1) {
      float ov = __shfl_xor(v1, msk); int oi = __shfl_xor(i1, msk);
      if (ov > v1 || (ov == v1 && oi < i1)) { v1 = ov; i1 = oi; }
    }
    // top-2
    float v2 = (e == i1) ? -1.f : prob; int i2 = e;
    #pragma unroll
    for (int msk = 1; msk <= 4; msk <<= 1) {
      float ov = __shfl_xor(v2, msk); int oi = __shfl_xor(i2, msk);
      if (ov > v2 || (ov == v2 && oi < i2)) { v2 = ov; i2 = oi; }
    }
    float wsum = v1 + v2;
    float wv = (e == i1) ? (v1 / wsum) : ((e == i2) ? (v2 / wsum) : 0.f);
    if (p == 0) wsc[(size_t)n * 8 + e] = wv * SCALING;
  }
}

// bf16 MFMA GEMM, C = A * B^T. 128x128 tile, BK=32, 4 waves (2x2), 4x4 frags each.
// MODE 0: write fp32 Cout. MODE 1: scale by wsc[row][col>>4], write bf16 to Vout (stride KAUG).
template<int MODE>
__global__ __launch_bounds__(256)
void k_gemm(const unsigned short* __restrict__ A, int lda,
            const unsigned short* __restrict__ B, int ldb, int K,
            float* __restrict__ Cout, int ldc,
            const float* __restrict__ wsc, unsigned short* __restrict__ Vout) {
  __shared__ alignas(16) unsigned short As[2][128 * 32];
  __shared__ alignas(16) unsigned short Bs[2][128 * 32];
  const int tid = threadIdx.x;
  const int w = tid >> 6, l = tid & 63;
  const int wr = w >> 1, wc = w & 1;
  const int bm = blockIdx.y, bn = blockIdx.x;
  const int NT = K >> 5;

  f32x4 acc[4][4];
  #pragma unroll
  for (int i = 0; i < 4; ++i)
    #pragma unroll
    for (int j = 0; j < 4; ++j) acc[i][j] = f32x4{0.f, 0.f, 0.f, 0.f};

  const unsigned short* Ablk = A + (size_t)bm * 128 * lda;
  const unsigned short* Bblk = B + (size_t)bn * 128 * ldb;

  auto stage = [&](int buf, int k0) {
    #pragma unroll
    for (int j = 0; j < 2; ++j) {
      int idx = (w * 2 + j) * 64 + l;   // 16B chunk id, 0..511
      int row = idx >> 2;
      int col = (idx & 3) * 8;
      const unsigned short* gpA = Ablk + (size_t)row * lda + k0 + col;
      const unsigned short* gpB = Bblk + (size_t)row * ldb + k0 + col;
      unsigned short* lpA = &As[buf][(w * 2 + j) * 512];  // wave-uniform base; HW adds lane*16B
      unsigned short* lpB = &Bs[buf][(w * 2 + j) * 512];
      __builtin_amdgcn_global_load_lds((const __attribute__((address_space(1))) unsigned int*)gpA,
                                       (__attribute__((address_space(3))) unsigned int*)lpA, 16, 0, 0);
      __builtin_amdgcn_global_load_lds((const __attribute__((address_space(1))) unsigned int*)gpB,
                                       (__attribute__((address_space(3))) unsigned int*)lpB, 16, 0, 0);
    }
  };

  stage(0, 0);
  for (int t = 0; t < NT; ++t) {
    __syncthreads();
    if (t + 1 < NT) stage((t + 1) & 1, (t + 1) << 5);
    const int buf = t & 1;
    const int ra = wr * 64 + (l & 15);
    const int rb = wc * 64 + (l & 15);
    const int ks = (l >> 4) * 8;
    bf16x8 af[4], bfr[4];
    #pragma unroll
    for (int mi = 0; mi < 4; ++mi)
      af[mi] = *(const bf16x8*)&As[buf][(ra + mi * 16) * 32 + ks];
    #pragma unroll
    for (int ni = 0; ni < 4; ++ni)
      bfr[ni] = *(const bf16x8*)&Bs[buf][(rb + ni * 16) * 32 + ks];
    #pragma unroll
    for (int mi = 0; mi < 4; ++mi)
      #pragma unroll
      for (int ni = 0; ni < 4; ++ni)
        acc[mi][ni] = __builtin_amdgcn_mfma_f32_16x16x32_bf16(af[mi], bfr[ni], acc[mi][ni], 0, 0, 0);
  }

  const int crow0 = bm * 128 + wr * 64 + (l >> 4) * 4;
  const int ccol0 = bn * 128 + wc * 64 + (l & 15);
  #pragma unroll
  for (int mi = 0; mi < 4; ++mi) {
    #pragma unroll
    for (int ni = 0; ni < 4; ++ni) {
      #pragma unroll
      for (int i = 0; i < 4; ++i) {
        int row = crow0 + mi * 16 + i;
        int col = ccol0 + ni * 16;
        if (MODE == 0) {
          Cout[(size_t)row * ldc + col] = acc[mi][ni][i];
        } else {
          float sgate = wsc[row * 8 + (col >> 4)];
          Vout[(size_t)row * KAUG + col] = f2b(acc[mi][ni][i] * sgate);
        }
      }
    }
  }
}

extern "C" void kernel_launch(void* const* d_in, const int* in_sizes, int n_in,
                              void* d_out, int out_size, void* d_ws, size_t ws_size,
                              hipStream_t stream) {
  const float* x  = (const float*)d_in[0];
  const float* wt = (const float*)d_in[1];
  const float* la = (const float*)d_in[2];
  const float* lb = (const float*)d_in[3];
  const float* rw = (const float*)d_in[4];
  float* out = (float*)d_out;
  char* ws = (char*)d_ws;

  // ws layout (bytes):
  //   A'  bf16 [8192][2176] @ 0          (35,651,584)
  //   B'  bf16 [2048][2176] @ 35,651,584 ( 8,912,896)
  //   Acat bf16 [128][2048] @ 44,564,480 (   524,288)
  //   wsc f32  [8192][8]    @ 45,088,768 (   262,144)
  unsigned short* Ap  = (unsigned short*)ws;
  unsigned short* Bp  = (unsigned short*)(ws + 35651584);
  unsigned short* Ac  = (unsigned short*)(ws + 44564480);
  float*          wsc = (float*)(ws + 45088768);

  k_convert_x<<<NTOK, 256, 0, stream>>>(x, Ap);
  k_build_B<<<OUT_F, 256, 0, stream>>>(wt, lb, Bp);
  k_convert_A<<<RANKE, 256, 0, stream>>>(la, Ac);
  k_router<<<256, 256, 0, stream>>>(x, rw, wsc);
  // Ax GEMM: [8192 x 2048] x [128 x 2048]^T -> scaled bf16 v into A'[:,2048:2176]
  k_gemm<1><<<dim3(1, 64), 256, 0, stream>>>(Ap, KAUG, Ac, IN_F, IN_F,
                                             nullptr, 0, wsc, Ap + IN_F);
  // Main GEMM: [8192 x 2176] x [2048 x 2176]^T -> fp32 out
  k_gemm<0><<<dim3(16, 64), 256, 0, stream>>>(Ap, KAUG, Bp, KAUG, KAUG,
                                              out, OUT_F, nullptr, nullptr);
}

// Round 2
// 151.320 us; speedup vs baseline: 1.5954x; 1.5954x over previous
//
#include <hip/hip_runtime.h>
#include <hip/hip_bf16.h>
#include <stdint.h>

#define IN_F   2048
#define OUT_F  2048
#define NTOK   8192
#define KAUG   2176   // 2048 + E*R
#define RANKE  128    // E*R
#define SCALING 2.0f
#define NT_MAIN 34    // KAUG / 64

typedef float  f32x4 __attribute__((ext_vector_type(4)));
typedef __bf16 bf16x8 __attribute__((ext_vector_type(8)));

#define GLOAD(g, l) __builtin_amdgcn_global_load_lds(                                   \
    (const __attribute__((address_space(1))) unsigned int*)(g),                          \
    (__attribute__((address_space(3))) unsigned int*)(l), 16, 0, 0)
#define PIN()    asm volatile("" ::: "memory")
#define BAR()    __builtin_amdgcn_s_barrier()
#define WAITL()  asm volatile("s_waitcnt lgkmcnt(0)" ::: "memory")
#define WAITV4() asm volatile("s_waitcnt vmcnt(4)" ::: "memory")
#define SB0()    __builtin_amdgcn_sched_barrier(0)

__device__ __forceinline__ unsigned short f2b(float f) {
  union { float f; unsigned u; } v; v.f = f;
  return (unsigned short)((v.u + 0x7FFFu + ((v.u >> 16) & 1u)) >> 16);
}

__device__ __forceinline__ uint4 pack8(float4 a, float4 b) {
  uint4 p;
  p.x = f2b(a.x) | ((unsigned)f2b(a.y) << 16);
  p.y = f2b(a.z) | ((unsigned)f2b(a.w) << 16);
  p.z = f2b(b.x) | ((unsigned)f2b(b.y) << 16);
  p.w = f2b(b.z) | ((unsigned)f2b(b.w) << 16);
  return p;
}

// ---------------------------------------------------------------------------
// Fused: x -> bf16 into A' (cols 0:2048)  +  router logits/softmax/top2 -> wsc
// Block = 256 threads handles 4 tokens. rw chunk held in registers across the
// 4 tokens (rw L2 traffic 64KB/block instead of 64KB/token).
// ---------------------------------------------------------------------------
__global__ __launch_bounds__(256)
void k_prep(const float* __restrict__ x, const float* __restrict__ rw,
            unsigned short* __restrict__ Ap, float* __restrict__ wsc) {
  const int t = threadIdx.x;
  const int w = t >> 6, l = t & 63;
  const int n0 = blockIdx.x * 4;

  // ---- convert: wave w converts token n0+w (2048 elems, 4 iters of 64x8)
  {
    const int n = n0 + w;
    const float4* src = (const float4*)(x + (size_t)n * IN_F);
    uint4* dst = (uint4*)(Ap + (size_t)n * KAUG);
    #pragma unroll
    for (int j = 0; j < 4; ++j) {
      int ch = j * 64 + l;                 // 8-elem chunk id 0..255
      float4 a = src[2 * ch], b = src[2 * ch + 1];
      dst[ch] = pack8(a, b);
    }
  }

  // ---- router partial dots: thread covers expert e = t&7, elems [p*64, p*64+64)
  const int e = t & 7, p = t >> 3;         // p in 0..31
  float4 wreg[16];
  {
    const float4* wp = (const float4*)(rw + (size_t)e * IN_F + p * 64);
    #pragma unroll
    for (int j = 0; j < 16; ++j) wreg[j] = wp[j];
  }
  float s[4];
  #pragma unroll
  for (int ti = 0; ti < 4; ++ti) {
    const float4* xp = (const float4*)(x + (size_t)(n0 + ti) * IN_F + p * 64);
    float acc = 0.f;
    #pragma unroll
    for (int j = 0; j < 16; ++j) {
      float4 a = xp[j], b = wreg[j];
      acc += a.x * b.x + a.y * b.y + a.z * b.z + a.w * b.w;
    }
    s[ti] = acc;
  }
  // reduce over lane bits 3,4,5 (p within wave)
  #pragma unroll
  for (int ti = 0; ti < 4; ++ti) {
    s[ti] += __shfl_xor(s[ti], 8);
    s[ti] += __shfl_xor(s[ti], 16);
    s[ti] += __shfl_xor(s[ti], 32);
  }
  __shared__ float red[4][4][8];           // [token][wave][expert]
  if (l < 8) {
    #pragma unroll
    for (int ti = 0; ti < 4; ++ti) red[ti][w][l] = s[ti];
  }
  __syncthreads();
  // wave w finalizes token n0+w; lanes 0..7 hold expert l
  if (l < 8) {
    float tot = red[w][0][l] + red[w][1][l] + red[w][2][l] + red[w][3][l];
    float m = tot;
    m = fmaxf(m, __shfl_xor(m, 1));
    m = fmaxf(m, __shfl_xor(m, 2));
    m = fmaxf(m, __shfl_xor(m, 4));
    float ex = expf(tot - m);
    float dn = ex;
    dn += __shfl_xor(dn, 1);
    dn += __shfl_xor(dn, 2);
    dn += __shfl_xor(dn, 4);
    float prob = ex / dn;
    float v1 = prob; int i1 = l;
    #pragma unroll
    for (int msk = 1; msk <= 4; msk <<= 1) {
      float ov = __shfl_xor(v1, msk); int oi = __shfl_xor(i1, msk);
      if (ov > v1 || (ov == v1 && oi < i1)) { v1 = ov; i1 = oi; }
    }
    float v2 = (l == i1) ? -1.f : prob; int i2 = l;
    #pragma unroll
    for (int msk = 1; msk <= 4; msk <<= 1) {
      float ov = __shfl_xor(v2, msk); int oi = __shfl_xor(i2, msk);
      if (ov > v2 || (ov == v2 && oi < i2)) { v2 = ov; i2 = oi; }
    }
    float wsum = v1 + v2;
    float wv = (l == i1) ? (v1 / wsum) : ((l == i2) ? (v2 / wsum) : 0.f);
    wsc[(size_t)(n0 + w) * 8 + l] = wv * SCALING;
  }
}

// B'[o][0:2048]=weight[o][:], B'[o][2048+e*16+r]=lora_B[e][o][r]
__global__ void k_build_B(const float* __restrict__ w, const float* __restrict__ lb,
                          unsigned short* __restrict__ Bp) {
  int o = blockIdx.x;
  int t = threadIdx.x;
  int c = t * 8;
  const float4* src = (const float4*)(w + (size_t)o * IN_F + c);
  float4 a = src[0], b = src[1];
  *(uint4*)(Bp + (size_t)o * KAUG + c) = pack8(a, b);
  if (t < RANKE) {
    float v = lb[((size_t)(t >> 4) * OUT_F + o) * 16 + (t & 15)];
    Bp[(size_t)o * KAUG + IN_F + t] = f2b(v);
  }
}

// lora_A flat [8][16][2048] == [128][2048] -> bf16 Acat
__global__ void k_convert_A(const float* __restrict__ la, unsigned short* __restrict__ Ac) {
  int i = blockIdx.x;
  int c = threadIdx.x * 8;
  const float4* src = (const float4*)(la + (size_t)i * IN_F + c);
  float4 a = src[0], b = src[1];
  *(uint4*)(Ac + (size_t)i * IN_F + c) = pack8(a, b);
}

// ---------------------------------------------------------------------------
// LoRA-A GEMM: V = gate-scaled (x_bf16 . Acat^T). 32x128 tile, 256 blocks,
// 4 waves (one per 32-col group). Swizzled LDS (chunk ^= row&7).
// ---------------------------------------------------------------------------
__global__ __launch_bounds__(256)
void k_lora(const unsigned short* __restrict__ Ap, const unsigned short* __restrict__ Ac,
            const float* __restrict__ wsc, unsigned short* __restrict__ Vout) {
  __shared__ alignas(16) unsigned short LA[2 * 2048];   //  2 x [32][64]
  __shared__ alignas(16) unsigned short LB[2 * 8192];   //  2 x [128][64]
  const int t = threadIdx.x, bm = blockIdx.x;
  const int w = t >> 6, l = t & 63;
  const int lr = l & 15, lq = l >> 4, lx = l & 7;
  const unsigned short* Ablk = Ap + (size_t)bm * 32 * KAUG;
  const int rr = t >> 3, cs = t & 7;
  const int sc = cs ^ (rr & 7);

  f32x4 acc[2][2];
  #pragma unroll
  for (int i = 0; i < 2; ++i)
    #pragma unroll
    for (int j = 0; j < 2; ++j) acc[i][j] = f32x4{0.f, 0.f, 0.f, 0.f};

  auto stg = [&](int buf, int kt) {
    GLOAD(Ablk + (size_t)rr * KAUG + kt * 64 + sc * 8, LA + buf * 2048 + w * 512);
    #pragma unroll
    for (int r = 0; r < 4; ++r)
      GLOAD(Ac + (size_t)(r * 32 + rr) * IN_F + kt * 64 + sc * 8,
            LB + buf * 8192 + r * 2048 + w * 512);
  };

  const int as0 = (lq ^ lx) * 8, as1 = ((4 + lq) ^ lx) * 8;

  stg(0, 0);
  __syncthreads();
  for (int kt = 0; kt < 32; ++kt) {
    const int buf = kt & 1;
    if (kt + 1 < 32) stg(buf ^ 1, kt + 1);
    bf16x8 aF[2][2], bF[2][2];
    #pragma unroll
    for (int mi = 0; mi < 2; ++mi) {
      aF[mi][0] = *(const bf16x8*)(LA + buf * 2048 + lr * 64 + mi * 1024 + as0);
      aF[mi][1] = *(const bf16x8*)(LA + buf * 2048 + lr * 64 + mi * 1024 + as1);
    }
    #pragma unroll
    for (int ni = 0; ni < 2; ++ni) {
      bF[ni][0] = *(const bf16x8*)(LB + buf * 8192 + w * 2048 + lr * 64 + ni * 1024 + as0);
      bF[ni][1] = *(const bf16x8*)(LB + buf * 8192 + w * 2048 + lr * 64 + ni * 1024 + as1);
    }
    #pragma unroll
    for (int mi = 0; mi < 2; ++mi)
      #pragma unroll
      for (int ni = 0; ni < 2; ++ni)
        #pragma unroll
        for (int ks = 0; ks < 2; ++ks)
          acc[mi][ni] = __builtin_amdgcn_mfma_f32_16x16x32_bf16(aF[mi][ks], bF[ni][ks], acc[mi][ni], 0, 0, 0);
    __syncthreads();
  }

  #pragma unroll
  for (int mi = 0; mi < 2; ++mi)
    #pragma unroll
    for (int ni = 0; ni < 2; ++ni)
      #pragma unroll
      for (int j = 0; j < 4; ++j) {
        int row = bm * 32 + mi * 16 + lq * 4 + j;
        int col = w * 32 + ni * 16 + lr;
        float sg = wsc[row * 8 + (col >> 4)];
        Vout[(size_t)row * KAUG + col] = f2b(acc[mi][ni][j] * sg);
      }
}

// ---------------------------------------------------------------------------
// Main GEMM: out[8192][2048] = A'[8192][2176] . B'[2048][2176]^T  (bf16->f32)
// 256x256 tile, BK=64, 8 waves (2M x 4N), 128KB LDS double-buffer,
// 4-phase K-step with counted vmcnt(4), chunk^(row&7) swizzle, XCD swizzle.
// ---------------------------------------------------------------------------
__global__ __launch_bounds__(512, 2)
void k_main(const unsigned short* __restrict__ A, const unsigned short* __restrict__ B,
            float* __restrict__ out) {
  __shared__ alignas(16) unsigned short LDS[65536];   // A: [0,32768) B: [32768,65536) shorts

  const int tid = threadIdx.x;
  const int id = blockIdx.x;
  const int wg = (id & 7) * 32 + (id >> 3);   // XCD-contiguous
  const int bn = wg >> 5, bm = wg & 31;       // 8 N-panels x 32 M-tiles
  const int w = tid >> 6, l = tid & 63;
  const int wr = w >> 2, wc = w & 3;
  const int lr = l & 15, lq = l >> 4, lx = l & 7;

  const unsigned short* Ablk = A + (size_t)bm * 256 * KAUG;
  const unsigned short* Bblk = B + (size_t)bn * 256 * KAUG;

  // staging addressing (per thread)
  const int rr = tid >> 3, cs = tid & 7;
  const int sc = cs ^ (rr & 7);
  const size_t gOfs = (size_t)rr * KAUG + sc * 8;
  unsigned short* const ldsW = LDS + w * 512;   // wave-uniform dest base

  // frag read offsets (shorts)
  const int aoff = wr * 8192 + lr * 64;
  const int boff = (wc >> 1) * 8192 + (wc & 1) * 4096 + lr * 64;
  const int as0 = (lq ^ lx) * 8, as1 = ((4 + lq) ^ lx) * 8;

  f32x4 acc[8][4];
  #pragma unroll
  for (int i = 0; i < 8; ++i)
    #pragma unroll
    for (int j = 0; j < 4; ++j) acc[i][j] = f32x4{0.f, 0.f, 0.f, 0.f};
  bf16x8 aF[8][2], bF[4][2];

  auto stg = [&](int op, int buf, int h, int kt) {
    const unsigned short* g = (op ? Bblk : Ablk) + (size_t)(h * 128) * KAUG + (size_t)kt * 64 + gOfs;
    unsigned short* ld = ldsW + op * 32768 + buf * 16384 + h * 8192;
    GLOAD(g, ld);
    GLOAD(g + (size_t)64 * KAUG, ld + 4096);
  };

#define QUAD(mq, nq)                                                                     \
  do {                                                                                   \
    _Pragma("unroll") for (int mi_ = 0; mi_ < 4; ++mi_)                                  \
    _Pragma("unroll") for (int ni_ = 0; ni_ < 2; ++ni_)                                  \
    _Pragma("unroll") for (int ks_ = 0; ks_ < 2; ++ks_)                                  \
      acc[(mq)*4 + mi_][(nq)*2 + ni_] = __builtin_amdgcn_mfma_f32_16x16x32_bf16(         \
          aF[(mq)*4 + mi_][ks_], bF[(nq)*2 + ni_][ks_], acc[(mq)*4 + mi_][(nq)*2 + ni_], \
          0, 0, 0);                                                                      \
  } while (0)

  // prologue: kt0 fully, kt1 A-halves (issue order matters for vmcnt counting)
  stg(0, 0, 0, 0); stg(0, 0, 1, 0); stg(1, 0, 0, 0); stg(1, 0, 1, 0);
  stg(0, 1, 0, 1); stg(0, 1, 1, 1);
  WAITV4(); PIN(); BAR();

  for (int i = 0; i < NT_MAIN; ++i) {
    const int buf = i & 1, nbuf = buf ^ 1;
    // ---- P1: read a[0..3], b[0..1]; stage B0(i+1); MFMA quad(0,0)
    #pragma unroll
    for (int mi = 0; mi < 4; ++mi) {
      aF[mi][0] = *(const bf16x8*)(LDS + buf * 16384 + aoff + mi * 1024 + as0);
      aF[mi][1] = *(const bf16x8*)(LDS + buf * 16384 + aoff + mi * 1024 + as1);
    }
    #pragma unroll
    for (int ni = 0; ni < 2; ++ni) {
      bF[ni][0] = *(const bf16x8*)(LDS + 32768 + buf * 16384 + boff + ni * 1024 + as0);
      bF[ni][1] = *(const bf16x8*)(LDS + 32768 + buf * 16384 + boff + ni * 1024 + as1);
    }
    if (i + 1 < NT_MAIN) stg(1, nbuf, 0, i + 1);
    PIN(); BAR(); WAITL(); SB0();
    __builtin_amdgcn_s_setprio(1); QUAD(0, 0); __builtin_amdgcn_s_setprio(0);
    PIN(); BAR();
    // ---- P2: read a[4..7], b[2..3]; stage B1(i+1); MFMA quad(0,1)
    #pragma unroll
    for (int mi = 4; mi < 8; ++mi) {
      aF[mi][0] = *(const bf16x8*)(LDS + buf * 16384 + aoff + mi * 1024 + as0);
      aF[mi][1] = *(const bf16x8*)(LDS + buf * 16384 + aoff + mi * 1024 + as1);
    }
    #pragma unroll
    for (int ni = 2; ni < 4; ++ni) {
      bF[ni][0] = *(const bf16x8*)(LDS + 32768 + buf * 16384 + boff + ni * 1024 + as0);
      bF[ni][1] = *(const bf16x8*)(LDS + 32768 + buf * 16384 + boff + ni * 1024 + as1);
    }
    if (i + 1 < NT_MAIN) stg(1, nbuf, 1, i + 1);
    PIN(); BAR(); WAITL(); SB0();
    __builtin_amdgcn_s_setprio(1); QUAD(0, 1); __builtin_amdgcn_s_setprio(0);
    PIN(); BAR();
    // ---- P3: stage A0(i+2) (kt-i reads of this buffer all completed at P2); quad(1,1)
    if (i + 2 < NT_MAIN) stg(0, buf, 0, i + 2);
    PIN(); BAR();
    __builtin_amdgcn_s_setprio(1); QUAD(1, 1); __builtin_amdgcn_s_setprio(0);
    PIN(); BAR();
    // ---- P4: stage A1(i+2); quad(1,0); counted vmcnt -> kt i+1 resident
    if (i + 2 < NT_MAIN) stg(0, buf, 1, i + 2);
    PIN(); BAR();
    __builtin_amdgcn_s_setprio(1); QUAD(1, 0); __builtin_amdgcn_s_setprio(0);
    WAITV4();
    PIN(); BAR();
  }
#undef QUAD

  #pragma unroll
  for (int mi = 0; mi < 8; ++mi)
    #pragma unroll
    for (int ni = 0; ni < 4; ++ni)
      #pragma unroll
      for (int j = 0; j < 4; ++j) {
        int row = bm * 256 + wr * 128 + mi * 16 + lq * 4 + j;
        int col = bn * 256 + wc * 64 + ni * 16 + lr;
        out[(size_t)row * OUT_F + col] = acc[mi][ni][j];
      }
}

extern "C" void kernel_launch(void* const* d_in, const int* in_sizes, int n_in,
                              void* d_out, int out_size, void* d_ws, size_t ws_size,
                              hipStream_t stream) {
  const float* x  = (const float*)d_in[0];
  const float* wt = (const float*)d_in[1];
  const float* la = (const float*)d_in[2];
  const float* lb = (const float*)d_in[3];
  const float* rw = (const float*)d_in[4];
  float* out = (float*)d_out;
  char* ws = (char*)d_ws;

  unsigned short* Ap  = (unsigned short*)ws;                 // bf16 [8192][2176]
  unsigned short* Bp  = (unsigned short*)(ws + 35651584);    // bf16 [2048][2176]
  unsigned short* Ac  = (unsigned short*)(ws + 44564480);    // bf16 [128][2048]
  float*          wsc = (float*)(ws + 45088768);             // f32  [8192][8]

  k_prep<<<NTOK / 4, 256, 0, stream>>>(x, rw, Ap, wsc);
  k_build_B<<<OUT_F, 256, 0, stream>>>(wt, lb, Bp);
  k_convert_A<<<RANKE, 256, 0, stream>>>(la, Ac);
  k_lora<<<NTOK / 32, 256, 0, stream>>>(Ap, Ac, wsc, Ap + IN_F);
  k_main<<<256, 512, 0, stream>>>(Ap, Bp, out);
}

// Round 3
// 138.845 us; speedup vs baseline: 1.7388x; 1.0899x over previous
//
#include <hip/hip_runtime.h>
#include <hip/hip_bf16.h>
#include <stdint.h>

#define IN_F   2048
#define OUT_F  2048
#define NTOK   8192
#define KAUG   2176   // 2048 + E*R
#define RANKE  128    // E*R
#define SCALING 2.0f
#define NT_MAIN 34    // KAUG / 64

typedef float  f32x4 __attribute__((ext_vector_type(4)));
typedef __bf16 bf16x8 __attribute__((ext_vector_type(8)));

#define GLOAD(g, l) __builtin_amdgcn_global_load_lds(                                   \
    (const __attribute__((address_space(1))) unsigned int*)(g),                          \
    (__attribute__((address_space(3))) unsigned int*)(l), 16, 0, 0)
#define PIN()    asm volatile("" ::: "memory")
#define BAR()    __builtin_amdgcn_s_barrier()
#define WAITL()  asm volatile("s_waitcnt lgkmcnt(0)" ::: "memory")
#define WAITV0() asm volatile("s_waitcnt vmcnt(0)" ::: "memory")
#define WAITV5() asm volatile("s_waitcnt vmcnt(5)" ::: "memory")
#define WAITV8() asm volatile("s_waitcnt vmcnt(8)" ::: "memory")
#define SB0()    __builtin_amdgcn_sched_barrier(0)

__device__ __forceinline__ unsigned short f2b(float f) {
  union { float f; unsigned u; } v; v.f = f;
  return (unsigned short)((v.u + 0x7FFFu + ((v.u >> 16) & 1u)) >> 16);
}

__device__ __forceinline__ uint4 pack8(float4 a, float4 b) {
  uint4 p;
  p.x = f2b(a.x) | ((unsigned)f2b(a.y) << 16);
  p.y = f2b(a.z) | ((unsigned)f2b(a.w) << 16);
  p.z = f2b(b.x) | ((unsigned)f2b(b.y) << 16);
  p.w = f2b(b.z) | ((unsigned)f2b(b.w) << 16);
  return p;
}

// ---------------------------------------------------------------------------
// Merged pre-pass. Role by blockIdx:
//   [0,2048):     prep — x->bf16 A' (cols 0:2048) + router softmax/top2 -> wsc
//   [2048,4096):  build B' row (weight + lora_B)
//   [4096,4104):  convert lora_A -> Acat bf16
// ---------------------------------------------------------------------------
__global__ __launch_bounds__(256)
void k_pre(const float* __restrict__ x, const float* __restrict__ rw,
           const float* __restrict__ wt, const float* __restrict__ lb,
           const float* __restrict__ la,
           unsigned short* __restrict__ Ap, float* __restrict__ wsc,
           unsigned short* __restrict__ Bp, unsigned short* __restrict__ Ac) {
  const int bid = blockIdx.x;
  const int t = threadIdx.x;

  if (bid >= 4096) {          // ---- convert lora_A: 8 blocks x 16 rows
    const int r0 = (bid - 4096) * 16;
    #pragma unroll
    for (int j = 0; j < 16; ++j) {
      int ch = j * 256 + t;
      int row = r0 + (ch >> 8), col8 = ch & 255;
      const float4* src = (const float4*)(la + (size_t)row * IN_F + col8 * 8);
      *(uint4*)(Ac + (size_t)row * IN_F + col8 * 8) = pack8(src[0], src[1]);
    }
    return;
  }
  if (bid >= 2048) {          // ---- build B' row o
    const int o = bid - 2048;
    const int c = t * 8;
    const float4* src = (const float4*)(wt + (size_t)o * IN_F + c);
    *(uint4*)(Bp + (size_t)o * KAUG + c) = pack8(src[0], src[1]);
    if (t < RANKE) {
      float v = lb[((size_t)(t >> 4) * OUT_F + o) * 16 + (t & 15)];
      Bp[(size_t)o * KAUG + IN_F + t] = f2b(v);
    }
    return;
  }

  // ---- prep role: 4 tokens per block
  const int w = t >> 6, l = t & 63;
  const int n0 = bid * 4;
  {
    const int n = n0 + w;
    const float4* src = (const float4*)(x + (size_t)n * IN_F);
    uint4* dst = (uint4*)(Ap + (size_t)n * KAUG);
    #pragma unroll
    for (int j = 0; j < 4; ++j) {
      int ch = j * 64 + l;
      dst[ch] = pack8(src[2 * ch], src[2 * ch + 1]);
    }
  }
  const int e = t & 7, p = t >> 3;
  float4 wreg[16];
  {
    const float4* wp = (const float4*)(rw + (size_t)e * IN_F + p * 64);
    #pragma unroll
    for (int j = 0; j < 16; ++j) wreg[j] = wp[j];
  }
  float s[4];
  #pragma unroll
  for (int ti = 0; ti < 4; ++ti) {
    const float4* xp = (const float4*)(x + (size_t)(n0 + ti) * IN_F + p * 64);
    float acc = 0.f;
    #pragma unroll
    for (int j = 0; j < 16; ++j) {
      float4 a = xp[j], b = wreg[j];
      acc += a.x * b.x + a.y * b.y + a.z * b.z + a.w * b.w;
    }
    s[ti] = acc;
  }
  #pragma unroll
  for (int ti = 0; ti < 4; ++ti) {
    s[ti] += __shfl_xor(s[ti], 8);
    s[ti] += __shfl_xor(s[ti], 16);
    s[ti] += __shfl_xor(s[ti], 32);
  }
  __shared__ float red[4][4][8];
  if (l < 8) {
    #pragma unroll
    for (int ti = 0; ti < 4; ++ti) red[ti][w][l] = s[ti];
  }
  __syncthreads();
  if (l < 8) {
    float tot = red[w][0][l] + red[w][1][l] + red[w][2][l] + red[w][3][l];
    float m = tot;
    m = fmaxf(m, __shfl_xor(m, 1));
    m = fmaxf(m, __shfl_xor(m, 2));
    m = fmaxf(m, __shfl_xor(m, 4));
    float ex = expf(tot - m);
    float dn = ex;
    dn += __shfl_xor(dn, 1);
    dn += __shfl_xor(dn, 2);
    dn += __shfl_xor(dn, 4);
    float prob = ex / dn;
    float v1 = prob; int i1 = l;
    #pragma unroll
    for (int msk = 1; msk <= 4; msk <<= 1) {
      float ov = __shfl_xor(v1, msk); int oi = __shfl_xor(i1, msk);
      if (ov > v1 || (ov == v1 && oi < i1)) { v1 = ov; i1 = oi; }
    }
    float v2 = (l == i1) ? -1.f : prob; int i2 = l;
    #pragma unroll
    for (int msk = 1; msk <= 4; msk <<= 1) {
      float ov = __shfl_xor(v2, msk); int oi = __shfl_xor(i2, msk);
      if (ov > v2 || (ov == v2 && oi < i2)) { v2 = ov; i2 = oi; }
    }
    float wsum = v1 + v2;
    float wv = (l == i1) ? (v1 / wsum) : ((l == i2) ? (v2 / wsum) : 0.f);
    wsc[(size_t)(n0 + w) * 8 + l] = wv * SCALING;
  }
}

// ---------------------------------------------------------------------------
// LoRA-A GEMM: V = gate-scaled (x_bf16 . Acat^T). 32x128 tile, 256 blocks,
// 4 waves. Ring-3 LDS, counted vmcnt(5) (stage t+2 while computing t).
// ---------------------------------------------------------------------------
__global__ __launch_bounds__(256)
void k_lora(const unsigned short* __restrict__ Ap, const unsigned short* __restrict__ Ac,
            const float* __restrict__ wsc, unsigned short* __restrict__ Vout) {
  __shared__ alignas(16) unsigned short LA[3 * 2048];   // 3 x [32][64]
  __shared__ alignas(16) unsigned short LB[3 * 8192];   // 3 x [128][64]
  const int t = threadIdx.x, bm = blockIdx.x;
  const int w = t >> 6, l = t & 63;
  const int lr = l & 15, lq = l >> 4, lx = l & 7;
  const unsigned short* Ablk = Ap + (size_t)bm * 32 * KAUG;
  const int rr = t >> 3, cs = t & 7;
  const int sc = cs ^ (rr & 7);

  f32x4 acc[2][2];
  #pragma unroll
  for (int i = 0; i < 2; ++i)
    #pragma unroll
    for (int j = 0; j < 2; ++j) acc[i][j] = f32x4{0.f, 0.f, 0.f, 0.f};

  auto stg = [&](int buf, int kt) {
    GLOAD(Ablk + (size_t)rr * KAUG + kt * 64 + sc * 8, LA + buf * 2048 + w * 512);
    #pragma unroll
    for (int r = 0; r < 4; ++r)
      GLOAD(Ac + (size_t)(r * 32 + rr) * IN_F + kt * 64 + sc * 8,
            LB + buf * 8192 + r * 2048 + w * 512);
  };

  const int as0 = (lq ^ lx) * 8, as1 = ((4 + lq) ^ lx) * 8;

  stg(0, 0); stg(1, 1);
  for (int kt = 0; kt < 32; ++kt) {
    if (kt == 31) { WAITV0(); } else { WAITV5(); }
    PIN(); BAR();
    if (kt + 2 < 32) stg((kt + 2) % 3, kt + 2);
    const int buf = kt % 3;
    bf16x8 aF[2][2], bF[2][2];
    #pragma unroll
    for (int mi = 0; mi < 2; ++mi) {
      aF[mi][0] = *(const bf16x8*)(LA + buf * 2048 + lr * 64 + mi * 1024 + as0);
      aF[mi][1] = *(const bf16x8*)(LA + buf * 2048 + lr * 64 + mi * 1024 + as1);
    }
    #pragma unroll
    for (int ni = 0; ni < 2; ++ni) {
      bF[ni][0] = *(const bf16x8*)(LB + buf * 8192 + w * 2048 + lr * 64 + ni * 1024 + as0);
      bF[ni][1] = *(const bf16x8*)(LB + buf * 8192 + w * 2048 + lr * 64 + ni * 1024 + as1);
    }
    #pragma unroll
    for (int mi = 0; mi < 2; ++mi)
      #pragma unroll
      for (int ni = 0; ni < 2; ++ni)
        #pragma unroll
        for (int ks = 0; ks < 2; ++ks)
          acc[mi][ni] = __builtin_amdgcn_mfma_f32_16x16x32_bf16(aF[mi][ks], bF[ni][ks], acc[mi][ni], 0, 0, 0);
  }

  #pragma unroll
  for (int mi = 0; mi < 2; ++mi)
    #pragma unroll
    for (int ni = 0; ni < 2; ++ni)
      #pragma unroll
      for (int j = 0; j < 4; ++j) {
        int row = bm * 32 + mi * 16 + lq * 4 + j;
        int col = w * 32 + ni * 16 + lr;
        float sg = wsc[row * 8 + (col >> 4)];
        Vout[(size_t)row * KAUG + col] = f2b(acc[mi][ni][j] * sg);
      }
}

// ---------------------------------------------------------------------------
// Main GEMM: out[8192][2048] = A'[8192][2176] . B'[2048][2176]^T  (bf16->f32)
// 256x256 tile, BK=64, 8 waves (2Mx4N). 4 phases/K-tile; P1/P2 pure
// ds_read+MFMA; P3/P4 stage ALL of tile t+2 into buf(t) (reads retired by P2).
// Single vmcnt(8)/tile => 8 loads (4 half-tiles) in flight. 6 barriers/tile.
// ---------------------------------------------------------------------------
__global__ __launch_bounds__(512, 2)
void k_main(const unsigned short* __restrict__ A, const unsigned short* __restrict__ B,
            float* __restrict__ out) {
  __shared__ alignas(16) unsigned short LDS[65536];   // A: [0,32768) B: [32768,65536)

  const int tid = threadIdx.x;
  const int id = blockIdx.x;
  const int wg = (id & 7) * 32 + (id >> 3);   // XCD-contiguous
  const int bn = wg >> 5, bm = wg & 31;
  const int w = tid >> 6, l = tid & 63;
  const int wr = w >> 2, wc = w & 3;
  const int lr = l & 15, lq = l >> 4, lx = l & 7;

  const unsigned short* Ablk = A + (size_t)bm * 256 * KAUG;
  const unsigned short* Bblk = B + (size_t)bn * 256 * KAUG;

  const int rr = tid >> 3, cs = tid & 7;
  const int sc = cs ^ (rr & 7);
  const size_t gOfs = (size_t)rr * KAUG + sc * 8;
  unsigned short* const ldsW = LDS + w * 512;

  const int aoff = wr * 8192 + lr * 64;
  const int boff = (wc >> 1) * 8192 + (wc & 1) * 4096 + lr * 64;
  const int as0 = (lq ^ lx) * 8, as1 = ((4 + lq) ^ lx) * 8;

  f32x4 acc[8][4];
  #pragma unroll
  for (int i = 0; i < 8; ++i)
    #pragma unroll
    for (int j = 0; j < 4; ++j) acc[i][j] = f32x4{0.f, 0.f, 0.f, 0.f};
  bf16x8 aF[8][2], bF[4][2];

  auto stg = [&](int op, int buf, int h, int kt) {
    const unsigned short* g = (op ? Bblk : Ablk) + (size_t)(h * 128) * KAUG + (size_t)kt * 64 + gOfs;
    unsigned short* ld = ldsW + op * 32768 + buf * 16384 + h * 8192;
    GLOAD(g, ld);
    GLOAD(g + (size_t)64 * KAUG, ld + 4096);
  };

#define QUAD(mq, nq)                                                                     \
  do {                                                                                   \
    _Pragma("unroll") for (int mi_ = 0; mi_ < 4; ++mi_)                                  \
    _Pragma("unroll") for (int ni_ = 0; ni_ < 2; ++ni_)                                  \
    _Pragma("unroll") for (int ks_ = 0; ks_ < 2; ++ks_)                                  \
      acc[(mq)*4 + mi_][(nq)*2 + ni_] = __builtin_amdgcn_mfma_f32_16x16x32_bf16(         \
          aF[(mq)*4 + mi_][ks_], bF[(nq)*2 + ni_][ks_], acc[(mq)*4 + mi_][(nq)*2 + ni_], \
          0, 0, 0);                                                                      \
  } while (0)

  // prologue: tiles 0 and 1 fully staged; wait leaves tile 1's 8 loads in flight
  stg(0, 0, 0, 0); stg(0, 0, 1, 0); stg(1, 0, 0, 0); stg(1, 0, 1, 0);
  stg(0, 1, 0, 1); stg(0, 1, 1, 1); stg(1, 1, 0, 1); stg(1, 1, 1, 1);
  WAITV8(); PIN(); BAR();

  for (int t = 0; t < NT_MAIN; ++t) {
    const int buf = t & 1;
    // ---- P1: read a[0..3], b[0..1]; QUAD(0,0)
    #pragma unroll
    for (int mi = 0; mi < 4; ++mi) {
      aF[mi][0] = *(const bf16x8*)(LDS + buf * 16384 + aoff + mi * 1024 + as0);
      aF[mi][1] = *(const bf16x8*)(LDS + buf * 16384 + aoff + mi * 1024 + as1);
    }
    #pragma unroll
    for (int ni = 0; ni < 2; ++ni) {
      bF[ni][0] = *(const bf16x8*)(LDS + 32768 + buf * 16384 + boff + ni * 1024 + as0);
      bF[ni][1] = *(const bf16x8*)(LDS + 32768 + buf * 16384 + boff + ni * 1024 + as1);
    }
    PIN(); BAR(); WAITL(); SB0();
    __builtin_amdgcn_s_setprio(1); QUAD(0, 0); __builtin_amdgcn_s_setprio(0);
    PIN(); BAR();
    // ---- P2: read a[4..7], b[2..3]; QUAD(0,1). After this, all buf reads retired.
    #pragma unroll
    for (int mi = 4; mi < 8; ++mi) {
      aF[mi][0] = *(const bf16x8*)(LDS + buf * 16384 + aoff + mi * 1024 + as0);
      aF[mi][1] = *(const bf16x8*)(LDS + buf * 16384 + aoff + mi * 1024 + as1);
    }
    #pragma unroll
    for (int ni = 2; ni < 4; ++ni) {
      bF[ni][0] = *(const bf16x8*)(LDS + 32768 + buf * 16384 + boff + ni * 1024 + as0);
      bF[ni][1] = *(const bf16x8*)(LDS + 32768 + buf * 16384 + boff + ni * 1024 + as1);
    }
    PIN(); BAR(); WAITL(); SB0();
    __builtin_amdgcn_s_setprio(1); QUAD(0, 1); __builtin_amdgcn_s_setprio(0);
    PIN(); BAR();
    // ---- P3: stage halves 0 of tile t+2 into buf; QUAD(1,1)
    if (t + 2 < NT_MAIN) { stg(0, buf, 0, t + 2); stg(1, buf, 0, t + 2); }
    PIN();
    __builtin_amdgcn_s_setprio(1); QUAD(1, 1); __builtin_amdgcn_s_setprio(0);
    PIN(); BAR();
    // ---- P4: stage halves 1 of tile t+2; QUAD(1,0); vmcnt(8) -> tile t+1 resident
    if (t + 2 < NT_MAIN) { stg(0, buf, 1, t + 2); stg(1, buf, 1, t + 2); }
    PIN();
    __builtin_amdgcn_s_setprio(1); QUAD(1, 0); __builtin_amdgcn_s_setprio(0);
    if (t + 2 < NT_MAIN) { WAITV8(); } else { WAITV0(); }
    PIN(); BAR();
  }
#undef QUAD

  #pragma unroll
  for (int mi = 0; mi < 8; ++mi)
    #pragma unroll
    for (int ni = 0; ni < 4; ++ni)
      #pragma unroll
      for (int j = 0; j < 4; ++j) {
        int row = bm * 256 + wr * 128 + mi * 16 + lq * 4 + j;
        int col = bn * 256 + wc * 64 + ni * 16 + lr;
        out[(size_t)row * OUT_F + col] = acc[mi][ni][j];
      }
}

extern "C" void kernel_launch(void* const* d_in, const int* in_sizes, int n_in,
                              void* d_out, int out_size, void* d_ws, size_t ws_size,
                              hipStream_t stream) {
  const float* x  = (const float*)d_in[0];
  const float* wt = (const float*)d_in[1];
  const float* la = (const float*)d_in[2];
  const float* lb = (const float*)d_in[3];
  const float* rw = (const float*)d_in[4];
  float* out = (float*)d_out;
  char* ws = (char*)d_ws;

  unsigned short* Ap  = (unsigned short*)ws;                 // bf16 [8192][2176]
  unsigned short* Bp  = (unsigned short*)(ws + 35651584);    // bf16 [2048][2176]
  unsigned short* Ac  = (unsigned short*)(ws + 44564480);    // bf16 [128][2048]
  float*          wsc = (float*)(ws + 45088768);             // f32  [8192][8]

  k_pre<<<4104, 256, 0, stream>>>(x, rw, wt, lb, la, Ap, wsc, Bp, Ac);
  k_lora<<<NTOK / 32, 256, 0, stream>>>(Ap, Ac, wsc, Ap + IN_F);
  k_main<<<256, 512, 0, stream>>>(Ap, Bp, out);
}